// Round 1
// baseline (178.785 us; speedup 1.0000x reference)
//
#include <hip/hip_runtime.h>

#define HH 512
#define WW 512
#define NPIX (HH*WW)

// ---------------------------------------------------------------------------
// Kernel 1: surface masks  S = p & ~erode(p)  (4-connectivity, OOB = false)
// Also zero-inits the accumulators (ws is re-poisoned before every launch).
// ---------------------------------------------------------------------------
__global__ void surf_kernel(const float* __restrict__ pred,
                            const float* __restrict__ gt,
                            unsigned char* __restrict__ mA,
                            unsigned char* __restrict__ mB,
                            double* __restrict__ acc) {
    int idx = blockIdx.x * blockDim.x + threadIdx.x;
    if (idx == 0) { acc[0] = 0.0; acc[1] = 0.0; }
    if (idx >= NPIX) return;
    int r = idx / WW;
    int c = idx - r * WW;
    {
        bool center = pred[idx] != 0.0f;
        bool up    = (r > 0)      && (pred[idx - WW] != 0.0f);
        bool down  = (r < HH - 1) && (pred[idx + WW] != 0.0f);
        bool left  = (c > 0)      && (pred[idx - 1] != 0.0f);
        bool right = (c < WW - 1) && (pred[idx + 1] != 0.0f);
        mA[idx] = (center && !(up && down && left && right)) ? 1 : 0;
    }
    {
        bool center = gt[idx] != 0.0f;
        bool up    = (r > 0)      && (gt[idx - WW] != 0.0f);
        bool down  = (r < HH - 1) && (gt[idx + WW] != 0.0f);
        bool left  = (c > 0)      && (gt[idx - 1] != 0.0f);
        bool right = (c < WW - 1) && (gt[idx + 1] != 0.0f);
        mB[idx] = (center && !(up && down && left && right)) ? 1 : 0;
    }
}

// ---------------------------------------------------------------------------
// Kernel 2: per-column two-sweep vertical distance, squared.
// Mirrors the reference lax.scan exactly: carry init 1e6, carry = feat ? 0 : carry+1.
// One thread per (column, field); writes df in sweep 1, combines in sweep 2.
// All integer values < 2^24 so fp32 arithmetic is exact (matches JAX).
// ---------------------------------------------------------------------------
__global__ void col_kernel(const unsigned char* __restrict__ mA,
                           const unsigned char* __restrict__ mB,
                           float* __restrict__ g2a,
                           float* __restrict__ g2b) {
    int tid = blockIdx.x * blockDim.x + threadIdx.x;
    if (tid >= 2 * WW) return;
    const unsigned char* m = (tid < WW) ? mA : mB;
    float* g2 = (tid < WW) ? g2a : g2b;
    int c = tid & (WW - 1);
    float carry = 1e6f;
    for (int r = 0; r < HH; ++r) {
        carry = m[r * WW + c] ? 0.0f : (carry + 1.0f);
        g2[r * WW + c] = carry;                 // df (down sweep)
    }
    carry = 1e6f;
    for (int r = HH - 1; r >= 0; --r) {
        carry = m[r * WW + c] ? 0.0f : (carry + 1.0f);
        float g = fminf(g2[r * WW + c], carry); // min(df, db)
        g2[r * WW + c] = g * g;
    }
}

// ---------------------------------------------------------------------------
// Kernel 3: row-wise min-plus transform  d2[c] = min_j (g2[j] + (c-j)^2),
// fused with the masked reduction. One block per row; g2 rows staged in LDS
// (broadcast reads, conflict-free). Double accumulation, wave-reduce, one
// atomicAdd per wave.
// ---------------------------------------------------------------------------
__global__ __launch_bounds__(256) void row_kernel(
        const float* __restrict__ g2a, const float* __restrict__ g2b,
        const unsigned char* __restrict__ mA, const unsigned char* __restrict__ mB,
        double* __restrict__ acc) {
    __shared__ float sga[WW];
    __shared__ float sgb[WW];
    int r = blockIdx.x;
    int t = threadIdx.x;
    for (int c = t; c < WW; c += 256) {
        sga[c] = g2a[r * WW + c];
        sgb[c] = g2b[r * WW + c];
    }
    __syncthreads();

    double lnum = 0.0, lden = 0.0;
    for (int c0 = t; c0 < WW; c0 += 256) {
        float cf = (float)c0;
        float da = 3.0e38f, db = 3.0e38f;
        #pragma unroll 8
        for (int j = 0; j < WW; ++j) {
            float d  = cf - (float)j;
            float d2 = d * d;
            da = fminf(da, sga[j] + d2);
            db = fminf(db, sgb[j] + d2);
        }
        float wA = (float)mA[r * WW + c0];   // sm  (pred surface)
        float wB = (float)mB[r * WW + c0];   // spm (gt surface)
        // num = sum(dta * spm) + sum(dtb * sm); dta = dist to pred surface (field A)
        lnum += (double)(sqrtf(da) * wB + sqrtf(db) * wA);
        lden += (double)(wA + wB);
    }

    // wave64 butterfly reduce, then one atomic per wave
    for (int off = 32; off > 0; off >>= 1) {
        lnum += __shfl_down(lnum, off, 64);
        lden += __shfl_down(lden, off, 64);
    }
    if ((t & 63) == 0) {
        atomicAdd(&acc[0], lnum);
        atomicAdd(&acc[1], lden);
    }
}

// ---------------------------------------------------------------------------
// Kernel 4: finalize scalar
// ---------------------------------------------------------------------------
__global__ void fin_kernel(const double* __restrict__ acc, float* __restrict__ out) {
    if (threadIdx.x == 0 && blockIdx.x == 0) {
        out[0] = (float)(acc[0] / acc[1]);
    }
}

extern "C" void kernel_launch(void* const* d_in, const int* in_sizes, int n_in,
                              void* d_out, int out_size, void* d_ws, size_t ws_size,
                              hipStream_t stream) {
    const float* pred = (const float*)d_in[0];
    const float* gt   = (const float*)d_in[1];
    float* out = (float*)d_out;

    char* ws = (char*)d_ws;
    double* acc        = (double*)ws;                                   // 16 B
    float* g2a         = (float*)(ws + 256);                            // 1 MB
    float* g2b         = (float*)(ws + 256 + (size_t)NPIX * 4);         // 1 MB
    unsigned char* mA  = (unsigned char*)(ws + 256 + (size_t)NPIX * 8); // 256 KB
    unsigned char* mB  = mA + NPIX;                                     // 256 KB

    surf_kernel<<<(NPIX + 255) / 256, 256, 0, stream>>>(pred, gt, mA, mB, acc);
    col_kernel<<<4, 256, 0, stream>>>(mA, mB, g2a, g2b);
    row_kernel<<<HH, 256, 0, stream>>>(g2a, g2b, mA, mB, acc);
    fin_kernel<<<1, 64, 0, stream>>>(acc, out);
}

// Round 3
// 134.529 us; speedup vs baseline: 1.3290x; 1.3290x over previous
//
#include <hip/hip_runtime.h>

#define HH 512
#define WW 512
#define NPIX (HH*WW)

// ---------------------------------------------------------------------------
// Kernel 1: surface masks  S = p & ~erode(p) (4-conn, OOB=false), float4-in /
// uchar4-out. Thread 0 zero-inits accumulators + ticket (ws is re-poisoned).
// ---------------------------------------------------------------------------
__global__ __launch_bounds__(256) void surf_kernel(
        const float* __restrict__ pred, const float* __restrict__ gt,
        unsigned char* __restrict__ mA, unsigned char* __restrict__ mB,
        double* __restrict__ acc, unsigned int* __restrict__ ticket) {
    int idx4 = blockIdx.x * 256 + threadIdx.x;       // 0..65535, 4 px each
    if (idx4 == 0) { acc[0] = 0.0; acc[1] = 0.0; *ticket = 0u; }
    if (idx4 >= NPIX / 4) return;
    int r  = idx4 >> 7;                              // 128 float4 per row
    int c4 = (idx4 & 127) << 2;

    const float* srcs[2] = { pred, gt };
    unsigned char* dsts[2] = { mA, mB };
    #pragma unroll
    for (int f = 0; f < 2; ++f) {
        const float* x = srcs[f];
        float4 v = ((const float4*)x)[idx4];
        float4 u = (r > 0)      ? ((const float4*)x)[idx4 - 128] : make_float4(0,0,0,0);
        float4 d = (r < HH - 1) ? ((const float4*)x)[idx4 + 128] : make_float4(0,0,0,0);
        float lS = (c4 > 0)        ? x[r * WW + c4 - 1] : 0.0f;
        float rS = (c4 + 4 < WW)   ? x[r * WW + c4 + 4] : 0.0f;
        float vv[4] = { v.x, v.y, v.z, v.w };
        float uu[4] = { u.x, u.y, u.z, u.w };
        float dd[4] = { d.x, d.y, d.z, d.w };
        uchar4 out;
        unsigned char* o = (unsigned char*)&out;
        #pragma unroll
        for (int e = 0; e < 4; ++e) {
            int c = c4 + e;
            bool ctr = vv[e] != 0.0f;
            bool up  = (r > 0)      && (uu[e] != 0.0f);
            bool dn  = (r < HH - 1) && (dd[e] != 0.0f);
            bool lf  = (c > 0)      && ((e == 0 ? lS : vv[e - 1]) != 0.0f);
            bool rt  = (c < WW - 1) && ((e == 3 ? rS : vv[e + 1]) != 0.0f);
            o[e] = (ctr && !(up && dn && lf && rt)) ? 1 : 0;
        }
        ((uchar4*)dsts[f])[idx4] = out;
    }
}

// ---------------------------------------------------------------------------
// Kernel 2: vertical squared distance via column bitmask + clz/ffs search.
// Block b: column c = b>>1, field = b&1; 512 threads = one per row.
// Sentinel semantics match the reference scan exactly:
//   no feature above -> df = 1e6 + (r+1); none below -> db = 1e6 + (H-r).
// ---------------------------------------------------------------------------
__global__ __launch_bounds__(512) void col_kernel(
        const unsigned char* __restrict__ mA, const unsigned char* __restrict__ mB,
        float* __restrict__ g2a, float* __restrict__ g2b) {
    int b = blockIdx.x;
    int c = b >> 1;
    const unsigned char* m = (b & 1) ? mB : mA;
    float* g2 = (b & 1) ? g2b : g2a;
    int r = threadIdx.x;
    bool feat = m[r * WW + c] != 0;

    __shared__ unsigned long long bm[HH / 64];
    unsigned long long bal = __ballot(feat);
    int wave = r >> 6, lane = r & 63;
    if (lane == 0) bm[wave] = bal;
    __syncthreads();

    float df;
    {
        int w = wave;
        unsigned long long word = bm[w] & (~0ULL >> (63 - lane)); // bits 0..lane
        int found = -1;
        while (true) {
            if (word) { found = w * 64 + 63 - __clzll(word); break; }
            if (--w < 0) break;
            word = bm[w];
        }
        df = (found >= 0) ? (float)(r - found) : (float)(r + 1) + 1e6f;
    }
    float db;
    {
        int w = wave;
        unsigned long long word = bm[w] & (~0ULL << lane);        // bits lane..63
        int found = -1;
        while (true) {
            if (word) { found = w * 64 + (__ffsll((unsigned long long)word) - 1); break; }
            if (++w >= HH / 64) break;
            word = bm[w];
        }
        db = (found >= 0) ? (float)(found - r) : (float)(HH - r) + 1e6f;
    }
    float g = fminf(df, db);
    g2[r * WW + c] = g * g;
}

// ---------------------------------------------------------------------------
// Kernel 3: row-wise min-plus + fused masked reduction + last-block finalize.
// Block = row r; thread t handles c0 = t and c1 = t+256, both fields.
// g2a/g2b interleaved as float2 in LDS -> wide ds_reads under unroll.
// 2 sub-accumulators per (c, field) break the fmin dependency chain.
// ---------------------------------------------------------------------------
__global__ __launch_bounds__(256) void row_kernel(
        const float* __restrict__ g2a, const float* __restrict__ g2b,
        const unsigned char* __restrict__ mA, const unsigned char* __restrict__ mB,
        double* __restrict__ acc, unsigned int* __restrict__ ticket,
        float* __restrict__ out) {
    __shared__ float2 sg[WW];
    int r = blockIdx.x;
    int t = threadIdx.x;
    for (int c = t; c < WW; c += 256)
        sg[c] = make_float2(g2a[r * WW + c], g2b[r * WW + c]);
    __syncthreads();

    float c0f = (float)t, c1f = (float)(t + 256);
    float dA0 = 3e38f, dA0b = 3e38f, dA1 = 3e38f, dA1b = 3e38f;
    float dB0 = 3e38f, dB0b = 3e38f, dB1 = 3e38f, dB1b = 3e38f;
    #pragma unroll 4
    for (int j = 0; j < WW; j += 2) {
        float2 g0 = sg[j], g1 = sg[j + 1];
        float e0 = c0f - (float)j,       e1 = c1f - (float)j;
        float f0 = c0f - (float)(j + 1), f1 = c1f - (float)(j + 1);
        dA0  = fminf(dA0,  fmaf(e0, e0, g0.x));
        dB0  = fminf(dB0,  fmaf(e0, e0, g0.y));
        dA1  = fminf(dA1,  fmaf(e1, e1, g0.x));
        dB1  = fminf(dB1,  fmaf(e1, e1, g0.y));
        dA0b = fminf(dA0b, fmaf(f0, f0, g1.x));
        dB0b = fminf(dB0b, fmaf(f0, f0, g1.y));
        dA1b = fminf(dA1b, fmaf(f1, f1, g1.x));
        dB1b = fminf(dB1b, fmaf(f1, f1, g1.y));
    }
    float da0 = fminf(dA0, dA0b), db0 = fminf(dB0, dB0b);
    float da1 = fminf(dA1, dA1b), db1 = fminf(dB1, dB1b);

    float wA0 = (float)mA[r * WW + t];       float wB0 = (float)mB[r * WW + t];
    float wA1 = (float)mA[r * WW + t + 256]; float wB1 = (float)mB[r * WW + t + 256];
    // num = sum(dta * spm) + sum(dtb * sm);  dta = dist to pred surface (A)
    double lnum = (double)(sqrtf(da0) * wB0 + sqrtf(db0) * wA0
                         + sqrtf(da1) * wB1 + sqrtf(db1) * wA1);
    double lden = (double)(wA0 + wB0 + wA1 + wB1);

    for (int off = 32; off > 0; off >>= 1) {
        lnum += __shfl_down(lnum, off, 64);
        lden += __shfl_down(lden, off, 64);
    }
    if ((t & 63) == 0) {
        atomicAdd(&acc[0], lnum);
        atomicAdd(&acc[1], lden);
    }
    __syncthreads();                 // all waves of this block have issued atomics
    if (t == 0) {
        __threadfence();             // make this block's adds visible device-wide
        unsigned int old = atomicAdd(ticket, 1u);
        if (old == HH - 1) {         // last block finalizes
            __threadfence();
            double num = atomicAdd(&acc[0], 0.0);   // coherent read
            double den = atomicAdd(&acc[1], 0.0);
            out[0] = (float)(num / den);
        }
    }
}

extern "C" void kernel_launch(void* const* d_in, const int* in_sizes, int n_in,
                              void* d_out, int out_size, void* d_ws, size_t ws_size,
                              hipStream_t stream) {
    const float* pred = (const float*)d_in[0];
    const float* gt   = (const float*)d_in[1];
    float* out = (float*)d_out;

    char* ws = (char*)d_ws;
    double* acc         = (double*)ws;                                   // 16 B
    unsigned int* tick  = (unsigned int*)(ws + 16);                      // 4 B
    float* g2a          = (float*)(ws + 256);                            // 1 MB
    float* g2b          = (float*)(ws + 256 + (size_t)NPIX * 4);         // 1 MB
    unsigned char* mA   = (unsigned char*)(ws + 256 + (size_t)NPIX * 8); // 256 KB
    unsigned char* mB   = mA + NPIX;                                     // 256 KB

    surf_kernel<<<NPIX / 4 / 256, 256, 0, stream>>>(pred, gt, mA, mB, acc, tick);
    col_kernel<<<2 * WW, 512, 0, stream>>>(mA, mB, g2a, g2b);
    row_kernel<<<HH, 256, 0, stream>>>(g2a, g2b, mA, mB, acc, tick, out);
}

// Round 4
// 75.631 us; speedup vs baseline: 2.3639x; 1.7788x over previous
//
#include <hip/hip_runtime.h>

#define HH 512
#define WW 512
#define NPIX (HH*WW)

// ---------------------------------------------------------------------------
// Kernel 1: surface masks  S = p & ~erode(p) (4-conn, OOB=false), float4-in /
// uchar4-out. Thread 0 zero-inits the ticket (ws is re-poisoned every call).
// ---------------------------------------------------------------------------
__global__ __launch_bounds__(256) void surf_kernel(
        const float* __restrict__ pred, const float* __restrict__ gt,
        unsigned char* __restrict__ mA, unsigned char* __restrict__ mB,
        unsigned int* __restrict__ ticket) {
    int idx4 = blockIdx.x * 256 + threadIdx.x;       // 0..65535, 4 px each
    if (idx4 == 0) { *ticket = 0u; }
    if (idx4 >= NPIX / 4) return;
    int r  = idx4 >> 7;                              // 128 float4 per row
    int c4 = (idx4 & 127) << 2;

    const float* srcs[2] = { pred, gt };
    unsigned char* dsts[2] = { mA, mB };
    #pragma unroll
    for (int f = 0; f < 2; ++f) {
        const float* x = srcs[f];
        float4 v = ((const float4*)x)[idx4];
        float4 u = (r > 0)      ? ((const float4*)x)[idx4 - 128] : make_float4(0,0,0,0);
        float4 d = (r < HH - 1) ? ((const float4*)x)[idx4 + 128] : make_float4(0,0,0,0);
        float lS = (c4 > 0)        ? x[r * WW + c4 - 1] : 0.0f;
        float rS = (c4 + 4 < WW)   ? x[r * WW + c4 + 4] : 0.0f;
        float vv[4] = { v.x, v.y, v.z, v.w };
        float uu[4] = { u.x, u.y, u.z, u.w };
        float dd[4] = { d.x, d.y, d.z, d.w };
        uchar4 out;
        unsigned char* o = (unsigned char*)&out;
        #pragma unroll
        for (int e = 0; e < 4; ++e) {
            int c = c4 + e;
            bool ctr = vv[e] != 0.0f;
            bool up  = (r > 0)      && (uu[e] != 0.0f);
            bool dn  = (r < HH - 1) && (dd[e] != 0.0f);
            bool lf  = (c > 0)      && ((e == 0 ? lS : vv[e - 1]) != 0.0f);
            bool rt  = (c < WW - 1) && ((e == 3 ? rS : vv[e + 1]) != 0.0f);
            o[e] = (ctr && !(up && dn && lf && rt)) ? 1 : 0;
        }
        ((uchar4*)dsts[f])[idx4] = out;
    }
}

// ---------------------------------------------------------------------------
// Kernel 2: fused EDT (vertical + horizontal, early-exit outward scans),
// masked reduction, and finalize. Block = one row (512 threads, c = tid).
//
// Vertical: nearest feature row in column c found by probing r±k (coalesced:
// c = lane). Exact sentinel semantics: no feature -> g = 1e6 + min(r+1, H-r).
// Horizontal: d2[c] = min_j(g2[j] + (c-j)^2); probe j = c±k, stop when
// k^2 >= best (any farther j contributes >= k^2 — exact early exit).
// All values integer-exact in fp32 except the 1e6 sentinel squares, which
// round identically to the reference (same ops, same order).
// ---------------------------------------------------------------------------
__global__ __launch_bounds__(512) void edt_kernel(
        const unsigned char* __restrict__ mA, const unsigned char* __restrict__ mB,
        double* __restrict__ partials, unsigned int* __restrict__ ticket,
        float* __restrict__ out) {
    __shared__ float sga[WW];
    __shared__ float sgb[WW];
    __shared__ double lred[16];
    __shared__ int winner;
    int r = blockIdx.x;
    int c = threadIdx.x;

    bool fa = mA[r * WW + c] != 0;
    bool fb = mB[r * WW + c] != 0;

    // --- vertical nearest-feature distance (early exit, coalesced probes) ---
    int foundA = fa ? 0 : -1;
    int foundB = fb ? 0 : -1;
    for (int k = 1; k < HH && (foundA < 0 || foundB < 0); ++k) {
        bool up = (r - k) >= 0, dn = (r + k) < HH;
        if (foundA < 0) {
            bool hit = (up && mA[(r - k) * WW + c] != 0) ||
                       (dn && mA[(r + k) * WW + c] != 0);
            if (hit) foundA = k;
        }
        if (foundB < 0) {
            bool hit = (up && mB[(r - k) * WW + c] != 0) ||
                       (dn && mB[(r + k) * WW + c] != 0);
            if (hit) foundB = k;
        }
    }
    float sent = 1e6f + (float)((r + 1 < HH - r) ? (r + 1) : (HH - r));
    float ga = (foundA >= 0) ? (float)foundA : sent;
    float gb = (foundB >= 0) ? (float)foundB : sent;
    sga[c] = ga * ga;
    sgb[c] = gb * gb;
    __syncthreads();

    // --- horizontal min-plus with early exit ---
    float besta = sga[c];
    float bestb = sgb[c];
    for (int k = 1; k < WW; ++k) {
        float k2 = (float)(k * k);
        if (k2 >= besta && k2 >= bestb) break;
        int cl = c - k, cr = c + k;
        if (cl >= 0) {
            besta = fminf(besta, sga[cl] + k2);
            bestb = fminf(bestb, sgb[cl] + k2);
        }
        if (cr < WW) {
            besta = fminf(besta, sga[cr] + k2);
            bestb = fminf(bestb, sgb[cr] + k2);
        }
    }

    // --- masked reduction ---
    float wA = fa ? 1.0f : 0.0f;
    float wB = fb ? 1.0f : 0.0f;
    // num = sum(dta * spm) + sum(dtb * sm); dta = dist to pred surface (A)
    double lnum = (double)(sqrtf(besta) * wB + sqrtf(bestb) * wA);
    double lden = (double)(wA + wB);
    for (int off = 32; off > 0; off >>= 1) {
        lnum += __shfl_down(lnum, off, 64);
        lden += __shfl_down(lden, off, 64);
    }
    int wv = c >> 6;
    if ((c & 63) == 0) { lred[wv] = lnum; lred[8 + wv] = lden; }
    __syncthreads();
    if (c == 0) {
        double n = 0.0, d = 0.0;
        #pragma unroll
        for (int i = 0; i < 8; ++i) { n += lred[i]; d += lred[8 + i]; }
        partials[2 * r]     = n;
        partials[2 * r + 1] = d;
        __threadfence();                         // release partials
        unsigned int old = atomicAdd(ticket, 1u);
        winner = (old == HH - 1) ? 1 : 0;
    }
    __syncthreads();

    // --- last block finalizes: parallel sum of 512 row partials ---
    if (winner) {
        __threadfence();                         // acquire all partials
        double n = partials[2 * c];
        double d = partials[2 * c + 1];
        for (int off = 32; off > 0; off >>= 1) {
            n += __shfl_down(n, off, 64);
            d += __shfl_down(d, off, 64);
        }
        if ((c & 63) == 0) { lred[c >> 6] = n; lred[8 + (c >> 6)] = d; }
        __syncthreads();
        if (c == 0) {
            double nn = 0.0, dd = 0.0;
            #pragma unroll
            for (int i = 0; i < 8; ++i) { nn += lred[i]; dd += lred[8 + i]; }
            out[0] = (float)(nn / dd);
        }
    }
}

extern "C" void kernel_launch(void* const* d_in, const int* in_sizes, int n_in,
                              void* d_out, int out_size, void* d_ws, size_t ws_size,
                              hipStream_t stream) {
    const float* pred = (const float*)d_in[0];
    const float* gt   = (const float*)d_in[1];
    float* out = (float*)d_out;

    char* ws = (char*)d_ws;
    unsigned int* tick = (unsigned int*)ws;                      // 4 B
    double* partials   = (double*)(ws + 256);                    // 512*2*8 = 8 KB
    unsigned char* mA  = (unsigned char*)(ws + 256 + 8192);      // 256 KB
    unsigned char* mB  = mA + NPIX;                              // 256 KB

    surf_kernel<<<NPIX / 4 / 256, 256, 0, stream>>>(pred, gt, mA, mB, tick);
    edt_kernel<<<HH, 512, 0, stream>>>(mA, mB, partials, tick, out);
}

// Round 5
// 73.510 us; speedup vs baseline: 2.4321x; 1.0288x over previous
//
#include <hip/hip_runtime.h>

#define HH 512
#define WW 512
#define NPIX (HH*WW)

// ---------------------------------------------------------------------------
// Kernel 1: combined surface mask  bit0 = pred-surface, bit1 = gt-surface.
// S = p & ~erode(p), 4-connectivity, OOB = false. float4-in / uchar4-out.
// Thread 0 zero-inits the ticket (ws is re-poisoned before every launch).
// ---------------------------------------------------------------------------
__global__ __launch_bounds__(256) void surf_kernel(
        const float* __restrict__ pred, const float* __restrict__ gt,
        unsigned char* __restrict__ mAB, unsigned int* __restrict__ ticket) {
    int idx4 = blockIdx.x * 256 + threadIdx.x;       // 0..65535, 4 px each
    if (idx4 == 0) { *ticket = 0u; }
    if (idx4 >= NPIX / 4) return;
    int r  = idx4 >> 7;                              // 128 float4 per row
    int c4 = (idx4 & 127) << 2;

    unsigned char bits[4] = {0, 0, 0, 0};
    const float* srcs[2] = { pred, gt };
    #pragma unroll
    for (int f = 0; f < 2; ++f) {
        const float* x = srcs[f];
        float4 v = ((const float4*)x)[idx4];
        float4 u = (r > 0)      ? ((const float4*)x)[idx4 - 128] : make_float4(0,0,0,0);
        float4 d = (r < HH - 1) ? ((const float4*)x)[idx4 + 128] : make_float4(0,0,0,0);
        float lS = (c4 > 0)        ? x[r * WW + c4 - 1] : 0.0f;
        float rS = (c4 + 4 < WW)   ? x[r * WW + c4 + 4] : 0.0f;
        float vv[4] = { v.x, v.y, v.z, v.w };
        float uu[4] = { u.x, u.y, u.z, u.w };
        float dd[4] = { d.x, d.y, d.z, d.w };
        #pragma unroll
        for (int e = 0; e < 4; ++e) {
            int c = c4 + e;
            bool ctr = vv[e] != 0.0f;
            bool up  = (r > 0)      && (uu[e] != 0.0f);
            bool dn  = (r < HH - 1) && (dd[e] != 0.0f);
            bool lf  = (c > 0)      && ((e == 0 ? lS : vv[e - 1]) != 0.0f);
            bool rt  = (c < WW - 1) && ((e == 3 ? rS : vv[e + 1]) != 0.0f);
            if (ctr && !(up && dn && lf && rt)) bits[e] |= (1 << f);
        }
    }
    uchar4 out;
    out.x = bits[0]; out.y = bits[1]; out.z = bits[2]; out.w = bits[3];
    ((uchar4*)mAB)[idx4] = out;
}

// ---------------------------------------------------------------------------
// Kernel 2: fused EDT + masked reduction + finalize. Block = row r, c = tid.
// Vertical: nearest feature row probed in BATCHES of 4 (8 independent loads
// issued before any test -> one latency wait per batch, not four).
// Horizontal: d2[c] = min_j(g2[j] + (c-j)^2), batched the same way; exit when
// kb^2 >= best (skipped j's contribute >= best since g2 >= 0 — exact).
// fp32 roundings identical to the reference (same operands, same single ops).
// ---------------------------------------------------------------------------
__global__ __launch_bounds__(512) void edt_kernel(
        const unsigned char* __restrict__ mAB,
        double* __restrict__ partials, unsigned int* __restrict__ ticket,
        float* __restrict__ out) {
    __shared__ float2 s2[WW];
    __shared__ double lred[16];
    __shared__ int winner;
    int r = blockIdx.x;
    int c = threadIdx.x;

    unsigned int own = mAB[r * WW + c];
    bool fa = (own & 1u) != 0u;
    bool fb = (own & 2u) != 0u;

    // --- vertical nearest-feature distance, batched probes ---
    int foundA = fa ? 0 : -1;
    int foundB = fb ? 0 : -1;
    for (int kb = 1; kb < HH && (foundA < 0 || foundB < 0); kb += 4) {
        unsigned int mu[4], md[4];
        #pragma unroll
        for (int i = 0; i < 4; ++i) {
            int ku = kb + i;
            int ru = r - ku, rd = r + ku;
            mu[i] = (ru >= 0) ? (unsigned int)mAB[ru * WW + c] : 0u;
            md[i] = (rd < HH) ? (unsigned int)mAB[rd * WW + c] : 0u;
        }
        #pragma unroll
        for (int i = 0; i < 4; ++i) {
            unsigned int hit = mu[i] | md[i];
            if (foundA < 0 && (hit & 1u)) foundA = kb + i;
            if (foundB < 0 && (hit & 2u)) foundB = kb + i;
        }
    }
    float sent = 1e6f + (float)((r + 1 < HH - r) ? (r + 1) : (HH - r));
    float ga = (foundA >= 0) ? (float)foundA : sent;
    float gb = (foundB >= 0) ? (float)foundB : sent;
    s2[c] = make_float2(ga * ga, gb * gb);
    __syncthreads();

    // --- horizontal min-plus, batched with exact early exit ---
    float2 o2 = s2[c];
    float besta = o2.x, bestb = o2.y;
    for (int kb = 1; kb < WW; kb += 4) {
        float kk2 = (float)(kb * kb);
        if (kk2 >= besta && kk2 >= bestb) break;
        #pragma unroll
        for (int i = 0; i < 4; ++i) {
            int k = kb + i;
            float k2 = (float)(k * k);
            int cl = c - k, cr = c + k;
            if (cl >= 0) {
                float2 g = s2[cl];
                besta = fminf(besta, g.x + k2);
                bestb = fminf(bestb, g.y + k2);
            }
            if (cr < WW) {
                float2 g = s2[cr];
                besta = fminf(besta, g.x + k2);
                bestb = fminf(bestb, g.y + k2);
            }
        }
    }

    // --- masked reduction ---
    float wA = fa ? 1.0f : 0.0f;
    float wB = fb ? 1.0f : 0.0f;
    // num = sum(dta * spm) + sum(dtb * sm); dta = dist to pred surface (A = bit0)
    double lnum = (double)(sqrtf(besta) * wB + sqrtf(bestb) * wA);
    double lden = (double)(wA + wB);
    for (int off = 32; off > 0; off >>= 1) {
        lnum += __shfl_down(lnum, off, 64);
        lden += __shfl_down(lden, off, 64);
    }
    int wv = c >> 6;
    if ((c & 63) == 0) { lred[wv] = lnum; lred[8 + wv] = lden; }
    __syncthreads();
    if (c == 0) {
        double n = 0.0, d = 0.0;
        #pragma unroll
        for (int i = 0; i < 8; ++i) { n += lred[i]; d += lred[8 + i]; }
        partials[2 * r]     = n;
        partials[2 * r + 1] = d;
        __threadfence();                         // release partials
        unsigned int old = atomicAdd(ticket, 1u);
        winner = (old == HH - 1) ? 1 : 0;
    }
    __syncthreads();

    // --- last block finalizes: parallel sum of 512 row partials ---
    if (winner) {
        __threadfence();                         // acquire all partials
        double n = partials[2 * c];
        double d = partials[2 * c + 1];
        for (int off = 32; off > 0; off >>= 1) {
            n += __shfl_down(n, off, 64);
            d += __shfl_down(d, off, 64);
        }
        if ((c & 63) == 0) { lred[c >> 6] = n; lred[8 + (c >> 6)] = d; }
        __syncthreads();
        if (c == 0) {
            double nn = 0.0, dd = 0.0;
            #pragma unroll
            for (int i = 0; i < 8; ++i) { nn += lred[i]; dd += lred[8 + i]; }
            out[0] = (float)(nn / dd);
        }
    }
}

extern "C" void kernel_launch(void* const* d_in, const int* in_sizes, int n_in,
                              void* d_out, int out_size, void* d_ws, size_t ws_size,
                              hipStream_t stream) {
    const float* pred = (const float*)d_in[0];
    const float* gt   = (const float*)d_in[1];
    float* out = (float*)d_out;

    char* ws = (char*)d_ws;
    unsigned int* tick = (unsigned int*)ws;                      // 4 B
    double* partials   = (double*)(ws + 256);                    // 8 KB
    unsigned char* mAB = (unsigned char*)(ws + 256 + 8192);      // 256 KB

    surf_kernel<<<NPIX / 4 / 256, 256, 0, stream>>>(pred, gt, mAB, tick);
    edt_kernel<<<HH, 512, 0, stream>>>(mAB, partials, tick, out);
}